// Round 1
// baseline (781.120 us; speedup 1.0000x reference)
//
#include <hip/hip_runtime.h>

#define HWD (512*512)
#define Wd 512
#define Hd 512
#define Cd 256
#define Kd 21
#define Nd 2560

// ---------------------------------------------------------------------------
// Pass 1: inclusive row cumsum of feature_map[c][y][:], written TRANSPOSED to
// channel-last R[y][x][c].  One wave per (c,y) row; lane l owns elements
// [8l, 8l+8): serial scan of 8 + wave64 shfl_up scan of per-lane totals.
// rid = c*512 + y  (y fastest) so the 16-channel writers of each 64B line are
// blockIdx multiples of 128 apart -> same XCD -> L2 write-combining works.
// ---------------------------------------------------------------------------
__global__ __launch_bounds__(256) void k_rowscan(const float* __restrict__ f,
                                                 float* __restrict__ R) {
    const int wave = threadIdx.x >> 6;
    const int lane = threadIdx.x & 63;
    const int rid  = blockIdx.x * 4 + wave;     // 0 .. 131071
    const int c = rid >> 9;                     // 0 .. 255
    const int y = rid & 511;                    // 0 .. 511

    const float* row = f + (size_t)c * HWD + (size_t)y * Wd;
    float4 a = *(const float4*)(row + lane * 8);
    float4 b = *(const float4*)(row + lane * 8 + 4);

    float v0 = a.x;
    float v1 = v0 + a.y;
    float v2 = v1 + a.z;
    float v3 = v2 + a.w;
    float v4 = v3 + b.x;
    float v5 = v4 + b.y;
    float v6 = v5 + b.z;
    float v7 = v6 + b.w;

    // wave-inclusive scan of per-lane totals
    float s = v7;
    float x = s;
    #pragma unroll
    for (int d = 1; d < 64; d <<= 1) {
        float t = __shfl_up(x, d);
        if (lane >= d) x += t;
    }
    const float off = x - s;   // exclusive prefix for this lane

    float* dst = R + ((size_t)y * Wd + (size_t)lane * 8) * Cd + c;
    dst[0 * Cd] = v0 + off;
    dst[1 * Cd] = v1 + off;
    dst[2 * Cd] = v2 + off;
    dst[3 * Cd] = v3 + off;
    dst[4 * Cd] = v4 + off;
    dst[5 * Cd] = v5 + off;
    dst[6 * Cd] = v6 + off;
    dst[7 * Cd] = v7 + off;
}

// ---------------------------------------------------------------------------
// Pass 2: in-place inclusive column cumsum over y in channel-last layout.
// Thread owns one (x,c) column (i = x*256+c); fully coalesced each y step.
// Depth-8 manual pipeline keeps ~8 loads in flight per thread so the serial
// y-chain is latency-covered.
// ---------------------------------------------------------------------------
__global__ __launch_bounds__(256) void k_colscan(float* __restrict__ R) {
    const int i = blockIdx.x * 256 + threadIdx.x;   // 0 .. 131071
    const int S = Wd * Cd;                          // 131072 floats per y

    float v[8];
    #pragma unroll
    for (int j = 0; j < 8; ++j) v[j] = R[(size_t)j * S + i];

    float acc = 0.f;
    for (int y = 0; y < Hd; y += 8) {
        float nxt[8];
        if (y + 8 < Hd) {
            #pragma unroll
            for (int j = 0; j < 8; ++j) nxt[j] = R[(size_t)(y + 8 + j) * S + i];
        } else {
            #pragma unroll
            for (int j = 0; j < 8; ++j) nxt[j] = 0.f;
        }
        #pragma unroll
        for (int j = 0; j < 8; ++j) {
            acc += v[j];
            R[(size_t)(y + j) * S + i] = acc;
        }
        #pragma unroll
        for (int j = 0; j < 8; ++j) v[j] = nxt[j];
    }
}

// ---------------------------------------------------------------------------
// Argmax over K=21 classes per pixel -> u8 map.  First-max-wins (strict >).
// ---------------------------------------------------------------------------
__global__ __launch_bounds__(256) void k_argmax(const float* __restrict__ ncb,
                                                unsigned char* __restrict__ map) {
    const int p = blockIdx.x * 256 + threadIdx.x;   // 0 .. 262143
    float best = ncb[p];
    int bi = 0;
    #pragma unroll
    for (int k = 1; k < Kd; ++k) {
        float v = ncb[(size_t)k * HWD + p];
        if (v > best) { best = v; bi = k; }
    }
    map[p] = (unsigned char)bi;
}

// ---------------------------------------------------------------------------
// fg_score: one block per box; count pixels where argmax == label.
// Exact integer count == reference's one-hot integral path.
// ---------------------------------------------------------------------------
__global__ __launch_bounds__(256) void k_fg(const unsigned char* __restrict__ map,
                                            const int* __restrict__ boxes,
                                            const int* __restrict__ labels,
                                            float* __restrict__ fg) {
    const int n = blockIdx.x;
    const int x0 = boxes[n * 4 + 0];
    const int y0 = boxes[n * 4 + 1];
    const int x1 = boxes[n * 4 + 2];
    const int y1 = boxes[n * 4 + 3];
    const int lab = labels[n];
    const int lane = threadIdx.x & 63;
    const int wv   = threadIdx.x >> 6;
    const int w = x1 - x0;

    int cnt = 0;
    for (int yy = y0 + wv; yy < y1; yy += 4) {
        if (lane < w)
            cnt += (map[yy * Wd + x0 + lane] == lab) ? 1 : 0;
    }
    #pragma unroll
    for (int d = 32; d; d >>= 1) cnt += __shfl_down(cnt, d);

    __shared__ int sred[4];
    if (lane == 0) sred[wv] = cnt;
    __syncthreads();
    if (threadIdx.x == 0) {
        int tot = sred[0] + sred[1] + sred[2] + sred[3];
        float area = (float)(w * (y1 - y0));
        fg[n] = (float)tot / area;
    }
}

// ---------------------------------------------------------------------------
// pool: one block per box, thread = channel.  4 corner gathers from the
// channel-last integral (each corner = contiguous 1KB run across channels).
// ---------------------------------------------------------------------------
__global__ __launch_bounds__(256) void k_pool(const float* __restrict__ I,
                                              const int* __restrict__ boxes,
                                              float* __restrict__ pool) {
    const int n = blockIdx.x;
    const int c = threadIdx.x;
    const int x0 = boxes[n * 4 + 0];
    const int y0 = boxes[n * 4 + 1];
    const int x1 = boxes[n * 4 + 2];
    const int y1 = boxes[n * 4 + 3];
    const int S = Wd * Cd;

    float a = I[(size_t)(y1 - 1) * S + (size_t)(x1 - 1) * Cd + c];
    float b = (y0 > 0) ? I[(size_t)(y0 - 1) * S + (size_t)(x1 - 1) * Cd + c] : 0.f;
    float d = (x0 > 0) ? I[(size_t)(y1 - 1) * S + (size_t)(x0 - 1) * Cd + c] : 0.f;
    float e = (y0 > 0 && x0 > 0)
                  ? I[(size_t)(y0 - 1) * S + (size_t)(x0 - 1) * Cd + c] : 0.f;

    float area = (float)((x1 - x0) * (y1 - y0));
    pool[(size_t)n * Cd + c] = (a - b - d + e) / area;
}

extern "C" void kernel_launch(void* const* d_in, const int* in_sizes, int n_in,
                              void* d_out, int out_size, void* d_ws, size_t ws_size,
                              hipStream_t stream) {
    (void)in_sizes; (void)n_in; (void)out_size; (void)ws_size;

    const float* feature_map = (const float*)d_in[0];   // [256][512][512] f32
    const float* norm_cam_bg = (const float*)d_in[1];   // [21][512][512]  f32
    const int*   boxes       = (const int*)d_in[2];     // [2560][4] i32
    const int*   labels      = (const int*)d_in[3];     // [2560]    i32

    float* out_pool = (float*)d_out;                    // [2560][256]
    float* out_fg   = out_pool + (size_t)Nd * Cd;       // [2560]

    // workspace: u8 argmax map (256KB, aligned) then channel-last integral
    unsigned char* map = (unsigned char*)d_ws;
    float* I = (float*)((char*)d_ws + 262144);          // 512*512*256 f32 = 268.4MB

    k_rowscan<<<131072 / 4, 256, 0, stream>>>(feature_map, I);
    k_colscan<<<(Wd * Cd) / 256, 256, 0, stream>>>(I);
    k_argmax<<<HWD / 256, 256, 0, stream>>>(norm_cam_bg, map);
    k_fg<<<Nd, 256, 0, stream>>>(map, boxes, labels, out_fg);
    k_pool<<<Nd, 256, 0, stream>>>(I, boxes, out_pool);
}

// Round 2
// 239.262 us; speedup vs baseline: 3.2647x; 3.2647x over previous
//
#include <hip/hip_runtime.h>

#define HWD (512*512)
#define Wd 512
#define Hd 512
#define Cd 256
#define Kd 21
#define Nd 2560

// ---------------------------------------------------------------------------
// Pass 1: inclusive row cumsum of feature_map[c][y][:], channel-FIRST output
// I[c][y][x] (same layout as input) -> fully coalesced read AND write.
// One wave per (c,y) row; lane l owns elements [8l, 8l+8): serial scan of 8
// + wave64 shfl_up scan of per-lane totals.
// ---------------------------------------------------------------------------
__global__ __launch_bounds__(256) void k_rowscan(const float* __restrict__ f,
                                                 float* __restrict__ I) {
    const int wave = threadIdx.x >> 6;
    const int lane = threadIdx.x & 63;
    const int rid  = blockIdx.x * 4 + wave;     // 0 .. 131071  (= c*512 + y)

    const float* row = f + (size_t)rid * Wd;
    float4 a = *(const float4*)(row + lane * 8);
    float4 b = *(const float4*)(row + lane * 8 + 4);

    float v0 = a.x;
    float v1 = v0 + a.y;
    float v2 = v1 + a.z;
    float v3 = v2 + a.w;
    float v4 = v3 + b.x;
    float v5 = v4 + b.y;
    float v6 = v5 + b.z;
    float v7 = v6 + b.w;

    // wave-inclusive scan of per-lane totals
    float s = v7;
    float x = s;
    #pragma unroll
    for (int d = 1; d < 64; d <<= 1) {
        float t = __shfl_up(x, d);
        if (lane >= d) x += t;
    }
    const float off = x - s;   // exclusive prefix for this lane

    float* dst = I + (size_t)rid * Wd + lane * 8;
    float4 o0 = { v0 + off, v1 + off, v2 + off, v3 + off };
    float4 o1 = { v4 + off, v5 + off, v6 + off, v7 + off };
    *(float4*)(dst)     = o0;
    *(float4*)(dst + 4) = o1;
}

// ---------------------------------------------------------------------------
// Pass 2: in-place inclusive column cumsum over y, channel-first layout.
// Thread owns one (c,x) column; consecutive threads = consecutive x, so each
// y-step is coalesced (wave reads 256B runs).  Depth-8 manual pipeline keeps
// 8 loads in flight to cover the serial y-chain latency.
// ---------------------------------------------------------------------------
__global__ __launch_bounds__(256) void k_colscan(float* __restrict__ I) {
    const int i = blockIdx.x * 256 + threadIdx.x;   // 0 .. 131071 (= c*512 + x)
    const int c = i >> 9;
    const int x = i & 511;
    float* col = I + (size_t)c * HWD + x;           // stride Wd between y

    float v[8];
    #pragma unroll
    for (int j = 0; j < 8; ++j) v[j] = col[(size_t)j * Wd];

    float acc = 0.f;
    for (int y = 0; y < Hd; y += 8) {
        float nxt[8];
        if (y + 8 < Hd) {
            #pragma unroll
            for (int j = 0; j < 8; ++j) nxt[j] = col[(size_t)(y + 8 + j) * Wd];
        } else {
            #pragma unroll
            for (int j = 0; j < 8; ++j) nxt[j] = 0.f;
        }
        #pragma unroll
        for (int j = 0; j < 8; ++j) {
            acc += v[j];
            col[(size_t)(y + j) * Wd] = acc;
        }
        #pragma unroll
        for (int j = 0; j < 8; ++j) v[j] = nxt[j];
    }
}

// ---------------------------------------------------------------------------
// Argmax over K=21 classes per pixel -> u8 map.  First-max-wins (strict >).
// ---------------------------------------------------------------------------
__global__ __launch_bounds__(256) void k_argmax(const float* __restrict__ ncb,
                                                unsigned char* __restrict__ map) {
    const int p = blockIdx.x * 256 + threadIdx.x;   // 0 .. 262143
    float best = ncb[p];
    int bi = 0;
    #pragma unroll
    for (int k = 1; k < Kd; ++k) {
        float v = ncb[(size_t)k * HWD + p];
        if (v > best) { best = v; bi = k; }
    }
    map[p] = (unsigned char)bi;
}

// ---------------------------------------------------------------------------
// fg_score: one block per box; count pixels where argmax == label.
// Exact integer count == reference's one-hot integral path.
// ---------------------------------------------------------------------------
__global__ __launch_bounds__(256) void k_fg(const unsigned char* __restrict__ map,
                                            const int* __restrict__ boxes,
                                            const int* __restrict__ labels,
                                            float* __restrict__ fg) {
    const int n = blockIdx.x;
    const int x0 = boxes[n * 4 + 0];
    const int y0 = boxes[n * 4 + 1];
    const int x1 = boxes[n * 4 + 2];
    const int y1 = boxes[n * 4 + 3];
    const int lab = labels[n];
    const int lane = threadIdx.x & 63;
    const int wv   = threadIdx.x >> 6;
    const int w = x1 - x0;

    int cnt = 0;
    for (int yy = y0 + wv; yy < y1; yy += 4) {
        if (lane < w)
            cnt += (map[yy * Wd + x0 + lane] == lab) ? 1 : 0;
    }
    #pragma unroll
    for (int d = 32; d; d >>= 1) cnt += __shfl_down(cnt, d);

    __shared__ int sred[4];
    if (lane == 0) sred[wv] = cnt;
    __syncthreads();
    if (threadIdx.x == 0) {
        int tot = sred[0] + sred[1] + sred[2] + sred[3];
        float area = (float)(w * (y1 - y0));
        fg[n] = (float)tot / area;
    }
}

// ---------------------------------------------------------------------------
// pool: one block per box, thread = channel.  4 corner gathers from the
// channel-first integral (one 64B line per load; ~168MB total fetch).
// ---------------------------------------------------------------------------
__global__ __launch_bounds__(256) void k_pool(const float* __restrict__ I,
                                              const int* __restrict__ boxes,
                                              float* __restrict__ pool) {
    const int n = blockIdx.x;
    const int c = threadIdx.x;
    const int x0 = boxes[n * 4 + 0];
    const int y0 = boxes[n * 4 + 1];
    const int x1 = boxes[n * 4 + 2];
    const int y1 = boxes[n * 4 + 3];
    const float* Ic = I + (size_t)c * HWD;

    float a = Ic[(size_t)(y1 - 1) * Wd + (x1 - 1)];
    float b = (y0 > 0) ? Ic[(size_t)(y0 - 1) * Wd + (x1 - 1)] : 0.f;
    float d = (x0 > 0) ? Ic[(size_t)(y1 - 1) * Wd + (x0 - 1)] : 0.f;
    float e = (y0 > 0 && x0 > 0)
                  ? Ic[(size_t)(y0 - 1) * Wd + (x0 - 1)] : 0.f;

    float area = (float)((x1 - x0) * (y1 - y0));
    pool[(size_t)n * Cd + c] = (a - b - d + e) / area;
}

extern "C" void kernel_launch(void* const* d_in, const int* in_sizes, int n_in,
                              void* d_out, int out_size, void* d_ws, size_t ws_size,
                              hipStream_t stream) {
    (void)in_sizes; (void)n_in; (void)out_size; (void)ws_size;

    const float* feature_map = (const float*)d_in[0];   // [256][512][512] f32
    const float* norm_cam_bg = (const float*)d_in[1];   // [21][512][512]  f32
    const int*   boxes       = (const int*)d_in[2];     // [2560][4] i32
    const int*   labels      = (const int*)d_in[3];     // [2560]    i32

    float* out_pool = (float*)d_out;                    // [2560][256]
    float* out_fg   = out_pool + (size_t)Nd * Cd;       // [2560]

    // workspace: u8 argmax map (256KB, aligned) then channel-first integral
    unsigned char* map = (unsigned char*)d_ws;
    float* I = (float*)((char*)d_ws + 262144);          // 512*512*256 f32 = 268.4MB

    k_rowscan<<<131072 / 4, 256, 0, stream>>>(feature_map, I);
    k_colscan<<<(Wd * Cd) / 256, 256, 0, stream>>>(I);
    k_argmax<<<HWD / 256, 256, 0, stream>>>(norm_cam_bg, map);
    k_fg<<<Nd, 256, 0, stream>>>(map, boxes, labels, out_fg);
    k_pool<<<Nd, 256, 0, stream>>>(I, boxes, out_pool);
}